// Round 6
// baseline (74.280 us; speedup 1.0000x reference)
//
#include <hip/hip_runtime.h>
#include <math.h>

// Problem constants (static config)
#define NB 1024     // batches
#define NS 64       // steps S
#define NT 63       // T = S-1
#define NV 192      // N = S*3 variables
#define BW 7        // band half-width+1 (fallback kernel)
#define NC 314      // constraint rows (fallback kernel)
#define NG 16       // 1024/64 wave-groups

// ws regions (per group, per lane): lane-transposed layout slot*64+lane
#define IN_SLOTS 328   // coeffs 0..191, rhs 192..255, steps 256..318, iv 320..323
#define L_SLOTS  1536  // 8 per column (dinv, L1..L6, z) x 192
#define X_SLOTS  192
#define IN_COEF 0
#define IN_RHS  192
#define IN_STP  256
#define IN_IV   320

// ============================================================================
// K1: transpose inputs into lane-transposed ws layout (coalesced both sides).
// ============================================================================
__global__ __launch_bounds__(1024, 1)
void ode_tin(const float* __restrict__ coeffs,
             const float* __restrict__ rhs,
             const float* __restrict__ steps,
             const float* __restrict__ iv_rhs,
             float* __restrict__ wsIn)
{
    const int g   = blockIdx.x;
    const int tid = threadIdx.x;
    __shared__ float tile[64 * 65];

    for (int c = 0; c < 3; ++c) {
        for (int idx = tid; idx < 64 * 64; idx += 1024) {
            const int b = idx >> 6, i = idx & 63;
            tile[b * 65 + i] = coeffs[(size_t)g * 12288 + (size_t)b * 192 + c * 64 + i];
        }
        __syncthreads();
        for (int idx = tid; idx < 64 * 64; idx += 1024) {
            const int i = idx >> 6, l = idx & 63;
            wsIn[((size_t)g * IN_SLOTS + IN_COEF + c * 64 + i) * 64 + l] = tile[l * 65 + i];
        }
        __syncthreads();
    }
    for (int idx = tid; idx < 64 * 64; idx += 1024) {
        const int b = idx >> 6, i = idx & 63;
        tile[b * 65 + i] = rhs[(size_t)g * 4096 + idx];
    }
    __syncthreads();
    for (int idx = tid; idx < 64 * 64; idx += 1024) {
        const int i = idx >> 6, l = idx & 63;
        wsIn[((size_t)g * IN_SLOTS + IN_RHS + i) * 64 + l] = tile[l * 65 + i];
    }
    __syncthreads();
    for (int idx = tid; idx < 64 * 63; idx += 1024) {
        const int b = idx / 63, i = idx - b * 63;
        tile[b * 65 + i] = steps[(size_t)g * 4032 + idx];
    }
    __syncthreads();
    for (int idx = tid; idx < 63 * 64; idx += 1024) {
        const int i = idx >> 6, l = idx & 63;
        wsIn[((size_t)g * IN_SLOTS + IN_STP + i) * 64 + l] = tile[l * 65 + i];
    }
    __syncthreads();
    for (int idx = tid; idx < 64 * 4; idx += 1024) {
        const int b = idx >> 2, i = idx & 3;
        tile[b * 65 + i] = iv_rhs[(size_t)g * 256 + idx];
    }
    __syncthreads();
    for (int idx = tid; idx < 4 * 64; idx += 1024) {
        const int i = idx >> 6, l = idx & 63;
        wsIn[((size_t)g * IN_SLOTS + IN_IV + i) * 64 + l] = tile[l * 65 + i];
    }
}

// ============================================================================
// K2: twisted factorization with the two chains on SEPARATE WAVES.
// Block = 512 threads = 8 waves = 4 groups x {fwd wave, bwd wave}.
// 4 blocks -> 32 waves on 4 CUs -> 2 waves/SIMD (TLP fills latency).
// LDS exchange: bwd exports U-window+z; fwd computes middle 6x6, exports x_mid;
// then fwd does the top back-sub and bwd the bottom concurrently.
// Arithmetic is identical to the verified r5 kernel.
// ============================================================================
__global__ __launch_bounds__(512, 1)
void ode_fused4(const float* __restrict__ wsIn,
                float* __restrict__ wsL,
                float* __restrict__ wsX)
{
    const int tid  = threadIdx.x;
    const int wv   = tid >> 6;         // wave 0..7
    const int l    = tid & 63;
    const int grp  = wv >> 1;          // 0..3
    const int role = wv & 1;           // 0 = fwd chain, 1 = bwd chain
    const int g    = blockIdx.x * 4 + grp;

    const float* __restrict__ inA = wsIn + (size_t)g * IN_SLOTS * 64 + l;
    float* __restrict__ lnA = wsL + (size_t)g * L_SLOTS * 64 + l;
    float* __restrict__ xA  = wsX + (size_t)g * X_SLOTS * 64 + l;

    __shared__ float xch[4 * 33 * 64];   // per group: 27 exchange + 6 x_mid

#define SLI(i) inA[(size_t)(i) * 64]
#define SL(i)  lnA[(size_t)(i) * 64]
#define SX(i)  xA[(size_t)(i) * 64]
#define XCH(s) xch[((grp) * 33 + (s)) * 64 + l]

    // window W[p][k] (k>=p) + fused-solve window y — used by BOTH roles
    float W11=0,W12=0,W13=0,W14=0,W15=0,W16=0;
    float W22=0,W23=0,W24=0,W25=0,W26=0;
    float W33=0,W34=0,W35=0,W36=0;
    float W44=0,W45=0,W46=0;
    float W55=0,W56=0;
    float W66=0;
    float y1=0,y2=0,y3=0,y4=0,y5=0,y6=0;
    float xm0=0,xm1=0,xm2=0,xm3=0,xm4=0,xm5=0;

#define CHOL_COL(j, b0, b1, b2, b3, b4, b5, b6, rvv)                           \
    {                                                                          \
        const float t0_ = (b0) - (W11*W11 + W22*W22 + W33*W33 +                \
                                  W44*W44 + W55*W55 + W66*W66);                \
        const float di_ = rsqrtf(t0_);                                         \
        const float u1_ = (b1) - (W11*W12 + W22*W23 + W33*W34 +                \
                                  W44*W45 + W55*W56);                          \
        const float u2_ = (b2) - (W11*W13 + W22*W24 + W33*W35 + W44*W46);      \
        const float u3_ = (b3) - (W11*W14 + W22*W25 + W33*W36);                \
        const float u4_ = (b4) - (W11*W15 + W22*W26);                          \
        const float u5_ = (b5) - (W11*W16);                                    \
        const float u6_ = (b6);                                                \
        const float yj_ = ((rvv) - (W11*y1 + W22*y2 + W33*y3 +                 \
                                    W44*y4 + W55*y5 + W66*y6)) * di_;          \
        const float n1_ = u1_*di_, n2_ = u2_*di_, n3_ = u3_*di_;               \
        const float n4_ = u4_*di_, n5_ = u5_*di_, n6_ = u6_*di_;               \
        SL((j)*8 + 0) = di_; SL((j)*8 + 1) = n1_; SL((j)*8 + 2) = n2_;         \
        SL((j)*8 + 3) = n3_; SL((j)*8 + 4) = n4_; SL((j)*8 + 5) = n5_;         \
        SL((j)*8 + 6) = n6_; SL((j)*8 + 7) = yj_;                              \
        W66 = W56;                                                             \
        W55 = W45; W56 = W46;                                                  \
        W44 = W34; W45 = W35; W46 = W36;                                       \
        W33 = W23; W34 = W24; W35 = W25; W36 = W26;                            \
        W22 = W12; W23 = W13; W24 = W14; W25 = W15; W26 = W16;                 \
        W11 = n1_; W12 = n2_; W13 = n3_; W14 = n4_; W15 = n5_; W16 = n6_;      \
        y6 = y5; y5 = y4; y4 = y3; y3 = y2; y2 = y1; y1 = yj_;                 \
    }

    if (role == 0) {
        // ---- FWD chain: steps 0..30, cols 0..92 ----
        const float iv00 = SLI(IN_IV + 0);
        const float iv01 = SLI(IN_IV + 1);
        const float iv10 = SLI(IN_IV + 2);
        const float iv11 = SLI(IN_IV + 3);
        float c0 = SLI(IN_COEF + 0), c1 = SLI(IN_COEF + 1), c2 = SLI(IN_COEF + 2);
        float r  = SLI(IN_RHS + 0);
        float p  = 0.f;
        float s  = SLI(IN_STP + 0);
        float sn = SLI(IN_STP + 1);

        for (int t = 0; t <= 30; ++t) {
            const float c0n = SLI(IN_COEF + 3*(t+1) + 0);
            const float c1n = SLI(IN_COEF + 3*(t+1) + 1);
            const float c2n = SLI(IN_COEF + 3*(t+1) + 2);
            const float rn  = SLI(IN_RHS + t + 1);
            const float snn = SLI(IN_STP + t + 2);

            const float mP  = (t >= 1) ? 1.f : 0.f;
            const float rg  = (t < 2) ? 1.f : 0.f;
            const float ivA = (t == 0) ? iv00 : ((t == 1) ? iv10 : 0.f);
            const float ivB = (t == 0) ? iv01 : ((t == 1) ? iv11 : 0.f);
            const float s2 = s*s, s3 = s2*s, p2 = p*p, p3 = p2*p;
            const float gt = p + s;
            const float A0 = c0*c0 + rg + 2.f*(1.f + mP);
            const float A1 = c0*c1 + s - p;
            const float A2 = c0*c2 + 0.5f*(s2 + p2);
            const float A4 = s;
            const float A5 = -0.5f*s2;
            const float B0 = c1*c1 + 3.f*(s2 + p2) + 2.f;
            const float B1 = c1*c2 + 1.5f*(s3 - p3);
            const float B2 = -s;
            const float B3 = -2.f*s2;
            const float B4 = s3 + (s + sn);
            const float Cv0 = c2*c2 + 1.25f*(s2*s2 + p2*p2) + gt*gt*mP;
            const float Cv1 = -0.5f*s2;
            const float Cv2 = -s3 - gt*mP;
            const float rv0 = c0*r + ivA;
            const float rv1 = c1*r + ivB;
            const float rv2 = c2*r;

            const int j0 = 3*t;
            CHOL_COL(j0 + 0, A0,  A1,  A2,  -2.f, A4,  A5,  0.f, rv0);
            CHOL_COL(j0 + 1, B0,  B1,  B2,  B3,  B4,  0.f, -1.f, rv1);
            CHOL_COL(j0 + 2, Cv0, Cv1, Cv2, 0.f, 0.f, 0.f, 0.f, rv2);

            p = s; s = sn; sn = snn;
            c0 = c0n; c1 = c1n; c2 = c2n; r = rn;
        }
    } else {
        // ---- BWD chain: steps 63..33, cols 191..99 (U factor) ----
        float c0 = SLI(IN_COEF + 189), c1 = SLI(IN_COEF + 190), c2 = SLI(IN_COEF + 191);
        float r  = SLI(IN_RHS + 63);
        float s  = 0.f;
        float p  = SLI(IN_STP + 62);
        float pp = SLI(IN_STP + 61);

        for (int t = 0; t <= 30; ++t) {
            const int bt = 63 - t;
            const float c0n = SLI(IN_COEF + 3*(bt-1) + 0);
            const float c1n = SLI(IN_COEF + 3*(bt-1) + 1);
            const float c2n = SLI(IN_COEF + 3*(bt-1) + 2);
            const float rn  = SLI(IN_RHS + bt - 1);
            const float ppn = SLI(IN_STP + bt - 3);

            const float mSb  = (bt < 63) ? 1.f : 0.f;
            const float mCNb = (bt < 62) ? 1.f : 0.f;
            const float s2 = s*s, s3 = s2*s, p2 = p*p, p3 = p2*p;
            const float gt = p + s;
            const float A0b = c0*c0 + 2.f*(mSb + 1.f);
            const float A1b = c0*c1 + s - p;
            const float A2b = c0*c2 + 0.5f*(s2 + p2);
            const float B0b = c1*c1 + 3.f*(s2 + p2) + mCNb + 1.f;
            const float B1b = c1*c2 + 1.5f*(s3 - p3);
            const float Cv0b = c2*c2 + 1.25f*(s2*s2 + p2*p2) + gt*gt*mSb;
            const float A4m = p;
            const float A5m = -0.5f*p2;
            const float B2m = -p;
            const float B3m = -2.f*p2;
            const float B4m = p3 + (p + s)*mSb;
            const float Cv1m = -0.5f*p2;
            const float Cv2m = -p3 - (pp + p);
            const float rv0b = c0*r;
            const float rv1b = c1*r;
            const float rv2b = c2*r;

            const int k0 = 3*bt;
            CHOL_COL(k0 + 2, Cv0b, B1b, A2b, 0.f, B4m, A5m, 0.f, rv2b);
            CHOL_COL(k0 + 1, B0b, A1b, Cv2m, B3m, A4m, 0.f, -1.f, rv1b);
            CHOL_COL(k0 + 0, A0b, Cv1m, B2m, -2.f, 0.f, 0.f, 0.f, rv0b);

            s = p; p = pp; pp = ppn;
            c0 = c0n; c1 = c1n; c2 = c2n; r = rn;
        }

        // export U-window + z to LDS for the fwd wave's middle block
        XCH(0)=W11;  XCH(1)=W12;  XCH(2)=W13;  XCH(3)=W14;  XCH(4)=W15;  XCH(5)=W16;
        XCH(6)=W22;  XCH(7)=W23;  XCH(8)=W24;  XCH(9)=W25;  XCH(10)=W26;
        XCH(11)=W33; XCH(12)=W34; XCH(13)=W35; XCH(14)=W36;
        XCH(15)=W44; XCH(16)=W45; XCH(17)=W46;
        XCH(18)=W55; XCH(19)=W56;
        XCH(20)=W66;
        XCH(21)=y1; XCH(22)=y2; XCH(23)=y3; XCH(24)=y4; XCH(25)=y5; XCH(26)=y6;
    }

    __syncthreads();

    if (role == 0) {
        // ---- middle block: cols 93..98, dense 6x6 (verified r5 formulas) ----
        const float V11=XCH(0),  V12=XCH(1),  V13=XCH(2),  V14=XCH(3),  V15=XCH(4),  V16=XCH(5);
        const float V22=XCH(6),  V23=XCH(7),  V24=XCH(8),  V25=XCH(9),  V26=XCH(10);
        const float V33=XCH(11), V34=XCH(12), V35=XCH(13), V36=XCH(14);
        const float V44=XCH(15), V45=XCH(16), V46=XCH(17);
        const float V55=XCH(18), V56=XCH(19);
        const float V66=XCH(20);
        const float bz1=XCH(21), bz2=XCH(22), bz3=XCH(23), bz4=XCH(24), bz5=XCH(25), bz6=XCH(26);

        const float pA  = SLI(IN_STP + 30), sA = SLI(IN_STP + 31);
        const float snA = SLI(IN_STP + 32), sB = SLI(IN_STP + 32);
        const float pB  = sA;
        const float c0A = SLI(IN_COEF + 93), c1A = SLI(IN_COEF + 94), c2A = SLI(IN_COEF + 95);
        const float c0B = SLI(IN_COEF + 96), c1B = SLI(IN_COEF + 97), c2B = SLI(IN_COEF + 98);
        const float rA  = SLI(IN_RHS + 31),  rB  = SLI(IN_RHS + 32);

        const float sA2 = sA*sA, sA3 = sA2*sA, pA2 = pA*pA, pA3 = pA2*pA;
        const float sB2 = sB*sB, sB3 = sB2*sB, pB2 = pB*pB, pB3 = pB2*pB;

        float S00 = c0A*c0A + 4.f;
        float S10 = c0A*c1A + sA - pA;
        float S20 = c0A*c2A + 0.5f*(sA2 + pA2);
        float S30 = -2.f;
        float S40 = sA;
        float S50 = -0.5f*sA2;
        float S11 = c1A*c1A + 3.f*(sA2 + pA2) + 2.f;
        float S21 = c1A*c2A + 1.5f*(sA3 - pA3);
        float S31 = -sA;
        float S41 = -2.f*sA2;
        float S51 = sA3 + (sA + snA);
        float S22 = c2A*c2A + 1.25f*(sA2*sA2 + pA2*pA2) + (pA + sA)*(pA + sA);
        float S32 = -0.5f*sA2;
        float S42 = -sA3 - (pA + sA);
        float S52 = 0.f;
        float S33 = c0B*c0B + 4.f;
        float S43 = c0B*c1B + sB - pB;
        float S53 = c0B*c2B + 0.5f*(sB2 + pB2);
        float S44 = c1B*c1B + 3.f*(sB2 + pB2) + 2.f;
        float S54 = c1B*c2B + 1.5f*(sB3 - pB3);
        float S55 = c2B*c2B + 1.25f*(sB2*sB2 + pB2*pB2) + (pB + sB)*(pB + sB);

        // subtract fwd Schur
        S00 -= W11*W11 + W22*W22 + W33*W33 + W44*W44 + W55*W55 + W66*W66;
        S10 -= W12*W11 + W23*W22 + W34*W33 + W45*W44 + W56*W55;
        S11 -= W12*W12 + W23*W23 + W34*W34 + W45*W45 + W56*W56;
        S20 -= W13*W11 + W24*W22 + W35*W33 + W46*W44;
        S21 -= W13*W12 + W24*W23 + W35*W34 + W46*W45;
        S22 -= W13*W13 + W24*W24 + W35*W35 + W46*W46;
        S30 -= W14*W11 + W25*W22 + W36*W33;
        S31 -= W14*W12 + W25*W23 + W36*W34;
        S32 -= W14*W13 + W25*W24 + W36*W35;
        S33 -= W14*W14 + W25*W25 + W36*W36;
        S40 -= W15*W11 + W26*W22;
        S41 -= W15*W12 + W26*W23;
        S42 -= W15*W13 + W26*W24;
        S43 -= W15*W14 + W26*W25;
        S44 -= W15*W15 + W26*W26;
        S50 -= W16*W11;
        S51 -= W16*W12;
        S52 -= W16*W13;
        S53 -= W16*W14;
        S54 -= W16*W15;
        S55 -= W16*W16;

        // subtract bwd Schur
        S00 -= V16*V16;
        S10 -= V15*V16;
        S11 -= V15*V15 + V26*V26;
        S20 -= V14*V16;
        S21 -= V14*V15 + V25*V26;
        S22 -= V14*V14 + V25*V25 + V36*V36;
        S30 -= V13*V16;
        S31 -= V13*V15 + V24*V26;
        S32 -= V13*V14 + V24*V25 + V35*V36;
        S33 -= V13*V13 + V24*V24 + V35*V35 + V46*V46;
        S40 -= V12*V16;
        S41 -= V12*V15 + V23*V26;
        S42 -= V12*V14 + V23*V25 + V34*V36;
        S43 -= V12*V13 + V23*V24 + V34*V35 + V45*V46;
        S44 -= V12*V12 + V23*V23 + V34*V34 + V45*V45 + V56*V56;
        S50 -= V11*V16;
        S51 -= V11*V15 + V22*V26;
        S52 -= V11*V14 + V22*V25 + V33*V36;
        S53 -= V11*V13 + V22*V24 + V33*V35 + V44*V46;
        S54 -= V11*V12 + V22*V23 + V33*V34 + V44*V45 + V55*V56;
        S55 -= V11*V11 + V22*V22 + V33*V33 + V44*V44 + V55*V55 + V66*V66;

        float fm0 = c0A*rA - (W11*y1 + W22*y2 + W33*y3 + W44*y4 + W55*y5 + W66*y6)
                           - (V16*bz1);
        float fm1 = c1A*rA - (W12*y1 + W23*y2 + W34*y3 + W45*y4 + W56*y5)
                           - (V15*bz1 + V26*bz2);
        float fm2 = c2A*rA - (W13*y1 + W24*y2 + W35*y3 + W46*y4)
                           - (V14*bz1 + V25*bz2 + V36*bz3);
        float fm3 = c0B*rB - (W14*y1 + W25*y2 + W36*y3)
                           - (V13*bz1 + V24*bz2 + V35*bz3 + V46*bz4);
        float fm4 = c1B*rB - (W15*y1 + W26*y2)
                           - (V12*bz1 + V23*bz2 + V34*bz3 + V45*bz4 + V56*bz5);
        float fm5 = c2B*rB - (W16*y1)
                           - (V11*bz1 + V22*bz2 + V33*bz3 + V44*bz4 + V55*bz5 + V66*bz6);

        const float md0 = rsqrtf(S00);
        const float M10 = S10*md0, M20 = S20*md0, M30 = S30*md0,
                    M40 = S40*md0, M50 = S50*md0;
        const float zm0 = fm0*md0;
        const float md1 = rsqrtf(S11 - M10*M10);
        const float M21 = (S21 - M20*M10)*md1;
        const float M31 = (S31 - M30*M10)*md1;
        const float M41 = (S41 - M40*M10)*md1;
        const float M51 = (S51 - M50*M10)*md1;
        const float zm1 = (fm1 - M10*zm0)*md1;
        const float md2 = rsqrtf(S22 - M20*M20 - M21*M21);
        const float M32 = (S32 - M30*M20 - M31*M21)*md2;
        const float M42 = (S42 - M40*M20 - M41*M21)*md2;
        const float M52 = (S52 - M50*M20 - M51*M21)*md2;
        const float zm2 = (fm2 - M20*zm0 - M21*zm1)*md2;
        const float md3 = rsqrtf(S33 - M30*M30 - M31*M31 - M32*M32);
        const float M43 = (S43 - M40*M30 - M41*M31 - M42*M32)*md3;
        const float M53 = (S53 - M50*M30 - M51*M31 - M52*M32)*md3;
        const float zm3 = (fm3 - M30*zm0 - M31*zm1 - M32*zm2)*md3;
        const float md4 = rsqrtf(S44 - M40*M40 - M41*M41 - M42*M42 - M43*M43);
        const float M54 = (S54 - M50*M40 - M51*M41 - M52*M42 - M53*M43)*md4;
        const float zm4 = (fm4 - M40*zm0 - M41*zm1 - M42*zm2 - M43*zm3)*md4;
        const float md5 = rsqrtf(S55 - M50*M50 - M51*M51 - M52*M52 - M53*M53 - M54*M54);
        const float zm5 = (fm5 - M50*zm0 - M51*zm1 - M52*zm2 - M53*zm3 - M54*zm4)*md5;

        xm5 = zm5*md5;
        xm4 = (zm4 - M54*xm5)*md4;
        xm3 = (zm3 - M43*xm4 - M53*xm5)*md3;
        xm2 = (zm2 - M32*xm3 - M42*xm4 - M52*xm5)*md2;
        xm1 = (zm1 - M21*xm2 - M31*xm3 - M41*xm4 - M51*xm5)*md1;
        xm0 = (zm0 - M10*xm1 - M20*xm2 - M30*xm3 - M40*xm4 - M50*xm5)*md0;

        SX(93) = xm0; SX(94) = xm1; SX(95) = xm2;
        SX(96) = xm3; SX(97) = xm4; SX(98) = xm5;
        XCH(27) = xm0; XCH(28) = xm1; XCH(29) = xm2;
        XCH(30) = xm3; XCH(31) = xm4; XCH(32) = xm5;
    }

    __syncthreads();

#define DECL8(P) float P##d = 0, P##1 = 0, P##2 = 0, P##3 = 0,                 \
                       P##4 = 0, P##5 = 0, P##6 = 0, P##y = 0;
#define LOAD8(P, j) { const size_t o8 = (size_t)(j)*8;                         \
        P##d = SL(o8 + 0); P##1 = SL(o8 + 1); P##2 = SL(o8 + 2);               \
        P##3 = SL(o8 + 3); P##4 = SL(o8 + 4); P##5 = SL(o8 + 5);               \
        P##6 = SL(o8 + 6); P##y = SL(o8 + 7); }
#define BSUB_T(P, j) {                                                         \
        const float rest = (P##6*x6 + P##5*x5) + (P##4*x4 + P##3*x3) + P##2*x2;\
        const float xr = ((P##y - rest) - P##1*x1) * P##d;                     \
        SX(j) = xr;                                                            \
        x6 = x5; x5 = x4; x4 = x3; x3 = x2; x2 = x1; x1 = xr; }
#define BSUB_B(P, j) {                                                         \
        const float rest = (P##6*w6 + P##5*w5) + (P##4*w4 + P##3*w3) + P##2*w2;\
        const float xr = ((P##y - rest) - P##1*w1) * P##d;                     \
        SX(j) = xr;                                                            \
        w6 = w5; w5 = w4; w4 = w3; w3 = w2; w2 = w1; w1 = xr; }

    if (role == 0) {
        // ---- top back-sub: cols 92..0 ----
        float x1 = xm0, x2 = xm1, x3 = xm2, x4 = xm3, x5 = xm4, x6 = xm5;
        DECL8(TP0) DECL8(TP1) DECL8(TP2)
        DECL8(TQ0) DECL8(TQ1) DECL8(TQ2)
        LOAD8(TP2, 92) LOAD8(TP1, 91) LOAD8(TP0, 90)
        for (int it = 0; it < 32; it += 2) {
            if (it <= 29) { const int tt = 29 - it;
                LOAD8(TQ2, 3*tt + 2) LOAD8(TQ1, 3*tt + 1) LOAD8(TQ0, 3*tt) }
            if (it <= 30) { const int ct = 30 - it;
                BSUB_T(TP2, 3*ct + 2) BSUB_T(TP1, 3*ct + 1) BSUB_T(TP0, 3*ct) }
            if (it + 1 <= 29) { const int tt = 28 - it;
                LOAD8(TP2, 3*tt + 2) LOAD8(TP1, 3*tt + 1) LOAD8(TP0, 3*tt) }
            if (it + 1 <= 30) { const int ct = 29 - it;
                BSUB_T(TQ2, 3*ct + 2) BSUB_T(TQ1, 3*ct + 1) BSUB_T(TQ0, 3*ct) }
        }
    } else {
        // ---- bottom back-sub: cols 99..191 ----
        const float m0 = XCH(27), m1 = XCH(28), m2 = XCH(29);
        const float m3 = XCH(30), m4 = XCH(31), m5 = XCH(32);
        float w1 = m5, w2 = m4, w3 = m3, w4 = m2, w5 = m1, w6 = m0;
        DECL8(BP0) DECL8(BP1) DECL8(BP2)
        DECL8(BQ0) DECL8(BQ1) DECL8(BQ2)
        LOAD8(BP0, 99) LOAD8(BP1, 100) LOAD8(BP2, 101)
        for (int it = 0; it < 32; it += 2) {
            if (it <= 29) { const int bb = 34 + it;
                LOAD8(BQ0, 3*bb) LOAD8(BQ1, 3*bb + 1) LOAD8(BQ2, 3*bb + 2) }
            if (it <= 30) { const int cb = 33 + it;
                BSUB_B(BP0, 3*cb) BSUB_B(BP1, 3*cb + 1) BSUB_B(BP2, 3*cb + 2) }
            if (it + 1 <= 29) { const int bb = 35 + it;
                LOAD8(BP0, 3*bb) LOAD8(BP1, 3*bb + 1) LOAD8(BP2, 3*bb + 2) }
            if (it + 1 <= 30) { const int cb = 34 + it;
                BSUB_B(BQ0, 3*cb) BSUB_B(BQ1, 3*cb + 1) BSUB_B(BQ2, 3*cb + 2) }
        }
    }

#undef SLI
#undef SL
#undef SX
#undef XCH
#undef CHOL_COL
#undef DECL8
#undef LOAD8
#undef BSUB_T
#undef BSUB_B
}

// ============================================================================
// K3: transpose x from ws X-region to out. Coalesced both sides.
// ============================================================================
__global__ __launch_bounds__(1024, 1)
void ode_tout(const float* __restrict__ wsX, float* __restrict__ out)
{
    const int g   = blockIdx.x;
    const int tid = threadIdx.x;
    __shared__ float tile[64 * 193];

    for (int idx = tid; idx < NV * 64; idx += 1024) {
        const int j = idx >> 6, l = idx & 63;
        tile[l * 193 + j] = wsX[((size_t)g * X_SLOTS + j) * 64 + l];
    }
    __syncthreads();
    for (int idx = tid; idx < 64 * NV; idx += 1024) {
        const int b = idx / NV, j = idx - b * NV;
        out[(size_t)g * 64 * NV + idx] = tile[b * 193 + j];
    }
}

// ============================================================================
// Fallback (round-1 kernel, known-pass): used only if ws is too small
// ============================================================================
__global__ __launch_bounds__(64, 1)
void ode_banded_solve(const float* __restrict__ coeffs,
                      const float* __restrict__ rhs,
                      const float* __restrict__ iv_rhs,
                      const float* __restrict__ steps,
                      float* __restrict__ out)
{
    const int b    = blockIdx.x;
    const int lane = threadIdx.x;

    __shared__ float band[NV * BW];
    __shared__ float rv[NV];
    __shared__ float stp[NT + 1];

    for (int i = lane; i < NV * BW; i += 64) band[i] = 0.0f;
    if (lane < NT) stp[lane] = steps[b * NT + lane];
    __syncthreads();

    {
        const int st = lane;
        const float c0 = coeffs[b * NV + st * 3 + 0];
        const float c1 = coeffs[b * NV + st * 3 + 1];
        const float c2 = coeffs[b * NV + st * 3 + 2];
        const float r  = rhs[b * NS + st];
        const float reg = (st < 2) ? 1.0f : 0.0f;
        atomicAdd(&band[(3 * st + 0) * BW + 0], c0 * c0 + reg);
        atomicAdd(&band[(3 * st + 1) * BW + 0], c1 * c1 + reg);
        atomicAdd(&band[(3 * st + 2) * BW + 0], c2 * c2);
        atomicAdd(&band[(3 * st + 1) * BW + 1], c1 * c0);
        atomicAdd(&band[(3 * st + 2) * BW + 1], c2 * c1);
        atomicAdd(&band[(3 * st + 2) * BW + 2], c2 * c0);
        float b0 = c0 * r, b1 = c1 * r, b2v = c2 * r;
        if (st < 2) {
            b0 += iv_rhs[b * 4 + st * 2 + 0];
            b1 += iv_rhs[b * 4 + st * 2 + 1];
        }
        rv[3 * st + 0] = b0;
        rv[3 * st + 1] = b1;
        rv[3 * st + 2] = b2v;
    }

    for (int t = lane; t < NC; t += 64) {
        int   cols[4];
        float vals[4];
        int   cnt;
        if (t < 126) {
            const int st = t >> 1, i = t & 1;
            const float s = stp[st];
            if (i == 0) {
                cols[0] = 3 * st + 0; vals[0] = 1.0f;
                cols[1] = 3 * st + 1; vals[1] = s;
                cols[2] = 3 * st + 2; vals[2] = 0.5f * s * s;
                cols[3] = 3 * st + 3; vals[3] = -1.0f;
                cnt = 4;
            } else {
                cols[0] = 3 * st + 1; vals[0] = s;
                cols[1] = 3 * st + 2; vals[1] = s * s;
                cols[2] = 3 * st + 4; vals[2] = -s;
                cnt = 3;
            }
        } else if (t < 188) {
            const int st = t - 126 + 1;
            const float cp = stp[st - 1] + stp[st];
            cols[0] = 3 * st - 2; vals[0] = -1.0f;
            cols[1] = 3 * st + 2; vals[1] = -cp;
            cols[2] = 3 * st + 4; vals[2] = 1.0f;
            cnt = 3;
        } else {
            const int tt = t - 188;
            const int st = tt >> 1, i = tt & 1;
            const float s = stp[st];
            if (i == 0) {
                cols[0] = 3 * st + 0; vals[0] = -1.0f;
                cols[1] = 3 * st + 3; vals[1] = 1.0f;
                cols[2] = 3 * st + 4; vals[2] = -s;
                cols[3] = 3 * st + 5; vals[3] = 0.5f * s * s;
                cnt = 4;
            } else {
                cols[0] = 3 * st + 1; vals[0] = s;
                cols[1] = 3 * st + 4; vals[1] = -s;
                cols[2] = 3 * st + 5; vals[2] = s * s;
                cnt = 3;
            }
        }
        for (int a = 0; a < cnt; ++a)
            for (int b2 = 0; b2 <= a; ++b2)
                atomicAdd(&band[cols[a] * BW + (cols[a] - cols[b2])],
                          vals[a] * vals[b2]);
    }
    __syncthreads();

    int pa = 0, pb = 0;
    {
        int idx = 0;
        for (int aa = 1; aa <= 6; ++aa)
            for (int bb = 1; bb <= aa; ++bb) {
                if (idx == lane) { pa = aa; pb = bb; }
                ++idx;
            }
    }
    const int sk = lane - 20;

    for (int j = 0; j < NV; ++j) {
        const int m = (NV - 1 - j < 6) ? (NV - 1 - j) : 6;
        const float diag = band[j * BW];
        const float d    = sqrtf(diag);
        const float dinv = 1.0f / d;

        const bool doU = (lane < 21) && (pa <= m);
        const bool doS = (lane >= 21) && (lane <= 26) && (sk <= m);
        float ca = 0.0f, cb = 0.0f, cs = 0.0f;
        if (doU) { ca = band[(j + pa) * BW + pa]; cb = band[(j + pb) * BW + pb]; }
        if (doS) { cs = band[(j + sk) * BW + sk]; }
        __syncthreads();

        if (lane == 0) band[j * BW] = d;
        if (doU) band[(j + pa) * BW + (pa - pb)] -= ca * cb * (dinv * dinv);
        if (doS) band[(j + sk) * BW + sk] = cs * dinv;
        __syncthreads();
    }

    for (int j = 0; j < NV; ++j) {
        const int m = (NV - 1 - j < 6) ? (NV - 1 - j) : 6;
        const float yj = rv[j] / band[j * BW];
        const bool doK = (lane >= 1) && (lane <= m);
        float sub = 0.0f, rj = 0.0f;
        if (doK) { sub = band[(j + lane) * BW + lane] * yj; rj = rv[j + lane]; }
        __syncthreads();
        if (lane == 0) rv[j] = yj;
        if (doK) rv[j + lane] = rj - sub;
        __syncthreads();
    }

    for (int j = NV - 1; j >= 0; --j) {
        const int m = (j < 6) ? j : 6;
        const float xj = rv[j] / band[j * BW];
        const bool doK = (lane >= 1) && (lane <= m);
        float sub = 0.0f, rj = 0.0f;
        if (doK) { sub = band[j * BW + lane] * xj; rj = rv[j - lane]; }
        __syncthreads();
        if (lane == 0) rv[j] = xj;
        if (doK) rv[j - lane] = rj - sub;
        __syncthreads();
    }

    for (int i = lane; i < NV; i += 64)
        out[b * NV + i] = rv[i];
}

extern "C" void kernel_launch(void* const* d_in, const int* in_sizes, int n_in,
                              void* d_out, int out_size, void* d_ws, size_t ws_size,
                              hipStream_t stream)
{
    const float* coeffs = (const float*)d_in[0];   // 1024*64*3
    const float* rhs    = (const float*)d_in[1];   // 1024*64
    const float* iv_rhs = (const float*)d_in[2];   // 1024*2*2
    const float* steps  = (const float*)d_in[3];   // 1024*63
    float* out = (float*)d_out;                    // 1024*192

    const size_t need = (size_t)(IN_SLOTS + L_SLOTS + X_SLOTS) * 64 * NG * sizeof(float); // ~8.4 MB

    if (ws_size >= need) {
        float* wsIn = (float*)d_ws;
        float* wsL  = wsIn + (size_t)IN_SLOTS * 64 * NG;
        float* wsX  = wsL  + (size_t)L_SLOTS * 64 * NG;
        ode_tin<<<dim3(NG), dim3(1024), 0, stream>>>(coeffs, rhs, steps, iv_rhs, wsIn);
        ode_fused4<<<dim3(4), dim3(512), 0, stream>>>(wsIn, wsL, wsX);
        ode_tout<<<dim3(NG), dim3(1024), 0, stream>>>(wsX, out);
    } else {
        ode_banded_solve<<<dim3(NB), dim3(64), 0, stream>>>(coeffs, rhs, iv_rhs,
                                                            steps, out);
    }
}